// Round 2
// baseline (52.997 us; speedup 1.0000x reference)
//
#include <hip/hip_runtime.h>
#include <math.h>

#define BATCH   2048
#define IN_DIM  512
#define NUM_OUT 256

#define CH  128              // i-chunk per LDS stage
#define NCH (IN_DIM / CH)    // 4

// S[b,o] = prod_i (1 - sigmoid(5*Wr[o,i]) * (1 - x[b,i]))
//        = prod_i fma(w, x, 1-w)
//
// Layout: o = lane (64 outputs per wave, all 4 waves share the o-tile and the
// LDS-staged W). Each wave owns 8 batch rows; x is wave-uniform -> scalar
// loads (no LDS, no per-lane 1-x). W staged in LDS as packed {w,1-w} float4
// covering 2 i's -> 1 ds_read_b128 per 2 i's per lane.
// grid = 4 o-tiles * 64 b-tiles = 256 blocks = 1/CU. VALU-bound: 2 ops/elem.
__global__ __launch_bounds__(256, 1)
void logic_and_kernel(const float* __restrict__ x,
                      const float* __restrict__ Wr,
                      float* __restrict__ out) {
  // [i2][o^swz] where i2 = i-pair index; entry = {w(i), 1-w(i), w(i+1), 1-w(i+1)}
  __shared__ float4 wS[CH / 2][64];   // 64 KB

  const int tid   = threadIdx.x;
  const int lane  = tid & 63;
  const int wv    = __builtin_amdgcn_readfirstlane(tid >> 6);  // wave 0..3
  const int ot    = blockIdx.x & 3;    // o-tile
  const int bt    = blockIdx.x >> 2;   // b-tile
  const int obase = ot * 64;
  const int bbase = bt * 32 + wv * 8;  // uniform per wave

  // staging seeds: thread covers o-rows {sr+16r} x i-quads {sl+16q}
  const int sr = tid >> 4;   // 0..15
  const int sl = tid & 15;   // 0..15

  const float* xw = x + (size_t)bbase * IN_DIM;  // uniform -> s_load path

  float acc[8];
  #pragma unroll
  for (int b = 0; b < 8; ++b) acc[b] = 1.f;

  // prefetch chunk 0 of W into regs
  float4 wr[8];
  #pragma unroll
  for (int r = 0; r < 4; ++r)
    #pragma unroll
    for (int q = 0; q < 2; ++q)
      wr[r * 2 + q] = *(const float4*)(Wr + (size_t)(obase + sr + 16 * r) * IN_DIM
                                          + (sl + 16 * q) * 4);

  bool wdead = false;

  for (int c = 0; c < NCH; ++c) {
    // ---- write staged chunk to LDS: sigmoid(5w) and 1-sigmoid, packed ----
    #pragma unroll
    for (int r = 0; r < 4; ++r) {
      #pragma unroll
      for (int q = 0; q < 2; ++q) {
        const float4 v = wr[r * 2 + q];
        const float w0 = __builtin_amdgcn_rcpf(1.f + __expf(v.x * -5.f));
        const float w1 = __builtin_amdgcn_rcpf(1.f + __expf(v.y * -5.f));
        const float w2 = __builtin_amdgcn_rcpf(1.f + __expf(v.z * -5.f));
        const float w3 = __builtin_amdgcn_rcpf(1.f + __expf(v.w * -5.f));
        const int iq  = sl + 16 * q;                 // i-quad 0..31
        const int col = (sr + 16 * r) ^ (iq & 7);    // XOR swizzle
        wS[iq * 2][col]     = make_float4(w0, 1.f - w0, w1, 1.f - w1);
        wS[iq * 2 + 1][col] = make_float4(w2, 1.f - w2, w3, 1.f - w3);
      }
    }
    __syncthreads();

    // prefetch next chunk of W (overlaps with compute below)
    const int cn = (c + 1 < NCH) ? c + 1 : c;
    #pragma unroll
    for (int r = 0; r < 4; ++r)
      #pragma unroll
      for (int q = 0; q < 2; ++q)
        wr[r * 2 + q] = *(const float4*)(Wr + (size_t)(obase + sr + 16 * r) * IN_DIM
                                            + cn * CH + (sl + 16 * q) * 4);

    // ---- compute: 32 phases of 4 i ----
    if (!wdead) {
      const float* xc = xw + c * CH;   // uniform
      #pragma unroll 8
      for (int p = 0; p < CH / 4; ++p) {
        const int col = lane ^ (p & 7);
        const float4 wa = wS[2 * p][col];       // {w(i0),1-w(i0),w(i1),1-w(i1)}
        const float4 wb = wS[2 * p + 1][col];   // i2, i3
        #pragma unroll
        for (int b = 0; b < 8; ++b) {
          const float x0 = xc[b * IN_DIM + 4 * p + 0];   // scalar loads
          const float x1 = xc[b * IN_DIM + 4 * p + 1];
          const float x2 = xc[b * IN_DIM + 4 * p + 2];
          const float x3 = xc[b * IN_DIM + 4 * p + 3];
          const float z0 = fmaf(wa.x, x0, wa.y);
          const float z1 = fmaf(wa.z, x1, wa.w);
          const float z2 = fmaf(wb.x, x2, wb.y);
          const float z3 = fmaf(wb.z, x3, wb.w);
          acc[b] *= (z0 * z1) * (z2 * z3);
        }
      }
    }

    // exact early exit: product sticks at 0. Barrier also guards LDS reuse.
    bool dead = true;
    #pragma unroll
    for (int b = 0; b < 8; ++b) dead &= (acc[b] == 0.f);
    wdead = (bool)__all((int)dead);
    if (__syncthreads_and((int)dead)) break;
  }

  #pragma unroll
  for (int b = 0; b < 8; ++b)
    out[(size_t)(bbase + b) * NUM_OUT + obase + lane] = acc[b];
}

extern "C" void kernel_launch(void* const* d_in, const int* in_sizes, int n_in,
                              void* d_out, int out_size, void* d_ws, size_t ws_size,
                              hipStream_t stream) {
  const float* x  = (const float*)d_in[0];   // [2048, 512]
  const float* Wr = (const float*)d_in[1];   // [256, 512]
  float* out      = (float*)d_out;           // [2048, 256]

  dim3 grid((NUM_OUT / 64) * (BATCH / 32));  // 4 * 64 = 256 blocks
  dim3 block(256);
  logic_and_kernel<<<grid, block, 0, stream>>>(x, Wr, out);
}

// Round 3
// 46.413 us; speedup vs baseline: 1.1419x; 1.1419x over previous
//
#include <hip/hip_runtime.h>
#include <math.h>

#define BATCH   2048
#define IN_DIM  512
#define NUM_OUT 256

// ---------------------------------------------------------------------------
// Pre-kernel: wp[i2][o] = { s(2*i2), 1-s(2*i2), s(2*i2+1), 1-s(2*i2+1) },
// where s(i) = sigmoid(5 * Wr[o][i]).  Layout: float4 wp[256][256] = 1 MB.
// Main-kernel reads wp[i2*256 + o] with o = lane -> perfectly coalesced.
__global__ __launch_bounds__(256)
void sigmoid_pack(const float* __restrict__ Wr, float4* __restrict__ wp) {
  const int t  = blockIdx.x * 256 + threadIdx.x;  // 65536 threads
  const int o  = t & (NUM_OUT - 1);               // lane-consecutive o
  const int i2 = t >> 8;                          // 0..255
  const float g0 = Wr[(size_t)o * IN_DIM + 2 * i2];
  const float g1 = Wr[(size_t)o * IN_DIM + 2 * i2 + 1];
  const float w0 = 1.f / (1.f + __expf(-5.f * g0));
  const float w1 = 1.f / (1.f + __expf(-5.f * g1));
  wp[(size_t)i2 * NUM_OUT + o] = make_float4(w0, 1.f - w0, w1, 1.f - w1);
}

// z for 4 i's of one batch row: z = w*x + (1-w)  (== 1 - w*(1-x))
__device__ __forceinline__ float z4(float4 wa, float4 wb, float4 xv) {
  const float z0 = fmaf(wa.x, xv.x, wa.y);
  const float z1 = fmaf(wa.z, xv.y, wa.w);
  const float z2 = fmaf(wb.x, xv.z, wb.y);
  const float z3 = fmaf(wb.z, xv.w, wb.w);
  return (z0 * z1) * (z2 * z3);
}

// One group = 16 i's x 4 batch rows. Issue all 24 loads first (W per-lane
// coalesced from L2; x wave-uniform broadcast from L1), then 128 VALU ops.
__device__ __forceinline__ void group16(const float4* __restrict__ wq,
                                        const float* __restrict__ xr, int g,
                                        float& a0, float& a1, float& a2, float& a3) {
  float4 W[8];
  float4 X[16];
  #pragma unroll
  for (int p = 0; p < 4; ++p) {
    W[2 * p]     = wq[(size_t)(8 * g + 2 * p) * NUM_OUT];
    W[2 * p + 1] = wq[(size_t)(8 * g + 2 * p + 1) * NUM_OUT];
  }
  #pragma unroll
  for (int p = 0; p < 4; ++p) {
    const float* xp = xr + 16 * g + 4 * p;
    X[4 * p + 0] = *(const float4*)(xp);
    X[4 * p + 1] = *(const float4*)(xp + IN_DIM);
    X[4 * p + 2] = *(const float4*)(xp + 2 * IN_DIM);
    X[4 * p + 3] = *(const float4*)(xp + 3 * IN_DIM);
  }
  #pragma unroll
  for (int p = 0; p < 4; ++p) {
    a0 *= z4(W[2 * p], W[2 * p + 1], X[4 * p + 0]);
    a1 *= z4(W[2 * p], W[2 * p + 1], X[4 * p + 1]);
    a2 *= z4(W[2 * p], W[2 * p + 1], X[4 * p + 2]);
    a3 *= z4(W[2 * p], W[2 * p + 1], X[4 * p + 3]);
  }
}

// Main: o = lane (64 o per wave), each wave owns 4 batch rows. No LDS, no
// barriers -> waves independent. grid = 4 o-tiles * 128 b-tiles = 512 blocks
// = 2 blocks/CU = 2 waves/SIMD.
__global__ __launch_bounds__(256, 2)
void logic_main(const float* __restrict__ x, const float4* __restrict__ wp,
                float* __restrict__ out) {
  const int tid  = threadIdx.x;
  const int lane = tid & 63;
  const int wv   = tid >> 6;          // wave 0..3
  const int ot   = blockIdx.x & 3;    // o-tile
  const int bt   = blockIdx.x >> 2;   // b-tile 0..127
  const int o    = ot * 64 + lane;
  const int b0   = bt * 16 + wv * 4;  // wave's 4 batch rows

  const float*  xr = x  + (size_t)b0 * IN_DIM;
  const float4* wq = wp + o;

  float a0 = 1.f, a1 = 1.f, a2 = 1.f, a3 = 1.f;

  // Phase A: i in [0, 320)
  for (int g = 0; g < 20; ++g) group16(wq, xr, g, a0, a1, a2, a3);

  // Exact per-wave early exit: products stick at 0 (z always finite).
  int dead = (a0 == 0.f) & (a1 == 0.f) & (a2 == 0.f) & (a3 == 0.f);
  if (!__all(dead)) {
    // Phase B: i in [320, 384)
    for (int g = 20; g < 24; ++g) group16(wq, xr, g, a0, a1, a2, a3);
    dead = (a0 == 0.f) & (a1 == 0.f) & (a2 == 0.f) & (a3 == 0.f);
    if (!__all(dead)) {
      // Phase C: i in [384, 512)
      for (int g = 24; g < 32; ++g) group16(wq, xr, g, a0, a1, a2, a3);
    }
  }

  float* op = out + (size_t)b0 * NUM_OUT + o;
  op[0 * NUM_OUT] = a0;
  op[1 * NUM_OUT] = a1;
  op[2 * NUM_OUT] = a2;
  op[3 * NUM_OUT] = a3;
}

// Fallback (ws too small): same structure, sigmoid recomputed inline from Wr.
__global__ __launch_bounds__(256, 2)
void logic_main_inline(const float* __restrict__ x, const float* __restrict__ Wr,
                       float* __restrict__ out) {
  const int tid  = threadIdx.x;
  const int lane = tid & 63;
  const int wv   = tid >> 6;
  const int ot   = blockIdx.x & 3;
  const int bt   = blockIdx.x >> 2;
  const int o    = ot * 64 + lane;
  const int b0   = bt * 16 + wv * 4;

  const float* xr = x + (size_t)b0 * IN_DIM;
  const float* wr = Wr + (size_t)o * IN_DIM;

  float a0 = 1.f, a1 = 1.f, a2 = 1.f, a3 = 1.f;

  for (int g = 0; g < 32; ++g) {
    #pragma unroll
    for (int p = 0; p < 4; ++p) {
      const int i = 16 * g + 4 * p;
      const float4 gv = *(const float4*)(wr + i);
      float4 wa, wb;
      const float w0 = 1.f / (1.f + __expf(-5.f * gv.x));
      const float w1 = 1.f / (1.f + __expf(-5.f * gv.y));
      const float w2 = 1.f / (1.f + __expf(-5.f * gv.z));
      const float w3 = 1.f / (1.f + __expf(-5.f * gv.w));
      wa = make_float4(w0, 1.f - w0, w1, 1.f - w1);
      wb = make_float4(w2, 1.f - w2, w3, 1.f - w3);
      a0 *= z4(wa, wb, *(const float4*)(xr + i));
      a1 *= z4(wa, wb, *(const float4*)(xr + IN_DIM + i));
      a2 *= z4(wa, wb, *(const float4*)(xr + 2 * IN_DIM + i));
      a3 *= z4(wa, wb, *(const float4*)(xr + 3 * IN_DIM + i));
    }
    if (g == 19 || g == 23) {
      const int dead = (a0 == 0.f) & (a1 == 0.f) & (a2 == 0.f) & (a3 == 0.f);
      if (__all(dead)) break;
    }
  }

  float* op = out + (size_t)b0 * NUM_OUT + o;
  op[0 * NUM_OUT] = a0;
  op[1 * NUM_OUT] = a1;
  op[2 * NUM_OUT] = a2;
  op[3 * NUM_OUT] = a3;
}

extern "C" void kernel_launch(void* const* d_in, const int* in_sizes, int n_in,
                              void* d_out, int out_size, void* d_ws, size_t ws_size,
                              hipStream_t stream) {
  const float* x  = (const float*)d_in[0];   // [2048, 512]
  const float* Wr = (const float*)d_in[1];   // [256, 512]
  float* out      = (float*)d_out;           // [2048, 256]

  const size_t wp_bytes = (size_t)(IN_DIM / 2) * NUM_OUT * sizeof(float4); // 1 MB

  if (ws_size >= wp_bytes && d_ws != nullptr) {
    float4* wp = (float4*)d_ws;
    sigmoid_pack<<<(IN_DIM / 2) * NUM_OUT / 256, 256, 0, stream>>>(Wr, wp);
    logic_main<<<(NUM_OUT / 64) * (BATCH / 16), 256, 0, stream>>>(x, wp, out);
  } else {
    logic_main_inline<<<(NUM_OUT / 64) * (BATCH / 16), 256, 0, stream>>>(x, Wr, out);
  }
}